// Round 1
// baseline (8818.004 us; speedup 1.0000x reference)
//
#include <hip/hip_runtime.h>
#include <hip/hip_bf16.h>

#define DEVI __device__ __forceinline__

namespace {

constexpr int nB = 256, nT = 64, nC = 4880, nD = 128, nH = 1024, nNT = 101, nND = 10;

typedef __attribute__((ext_vector_type(8))) short bfrag;   // 8 bf16 = 4 VGPR (MFMA A/B)
typedef __attribute__((ext_vector_type(4))) float ffrag;   // MFMA C/D
typedef __attribute__((ext_vector_type(4))) unsigned int uvec4;

DEVI ffrag mfma16(bfrag a, bfrag b, ffrag c) {
  return __builtin_amdgcn_mfma_f32_16x16x32_bf16(a, b, c, 0, 0, 0);
}

DEVI unsigned short f2b(float x) {
  __hip_bfloat16 h = __float2bfloat16(x);
  return *reinterpret_cast<unsigned short*>(&h);
}
DEVI float b2f(unsigned short u) {
  __hip_bfloat16 h;
  *reinterpret_cast<unsigned short*>(&h) = u;
  return __bfloat162float(h);
}
DEVI float sigm(float x) { return 1.f / (1.f + expf(-x)); }

// ---------------------------------------------------------------------------
// Double-buffered bf16 MFMA tile stream.
// Computes acc[s] += A_tile(32 rows x K) * W[s]_tile(32 rows x K)^T for a
// 32x32 output tile at (m0, n0). Block = 256 threads = 4 waves; wave (mq,nq)
// owns the 16x16 quadrant. A and W are row-major with K contiguous (bf16).
// LDS tiles are [32 rows][8 x 16B-blocks] with block-index XOR row swizzle
// so both the linear stage-writes and the fragment ds_read_b128 are
// conflict-free. Global loads for chunk ci+1 are issued before compute of
// chunk ci (reg double-buffer) to hide L2 latency at 1 block/CU.
// ---------------------------------------------------------------------------
template<int NS>
DEVI void mm_stream(ffrag (&acc)[NS],
                    const unsigned short* __restrict__ A, int lda, int K,
                    const unsigned short* const (&Wp)[NS], int ldw,
                    int m0, int n0, int tid, int lane, int mq, int nq,
                    unsigned short* As, unsigned short* Ws) {
  const int r = tid >> 3, blk = tid & 7;
  const int wrOff = (r * 8 + (blk ^ (r & 7))) * 8;   // ushort offset
  const int ra = mq * 16 + (lane & 15);              // A-frag row (m)
  const int rw = nq * 16 + (lane & 15);              // W-frag row (n)
  const int q = lane >> 4;                           // k-quadrant
  const int nc = K >> 6;                             // 64-wide K chunks

  // prologue: chunk 0 -> buffer 0
  uvec4 va = *(const uvec4*)(A + (size_t)(m0 + r) * lda + blk * 8);
  uvec4 vw[NS];
#pragma unroll
  for (int s = 0; s < NS; ++s)
    vw[s] = *(const uvec4*)(Wp[s] + (size_t)(n0 + r) * ldw + blk * 8);
  *(uvec4*)(As + wrOff) = va;
#pragma unroll
  for (int s = 0; s < NS; ++s) *(uvec4*)(Ws + s * 2048 + wrOff) = vw[s];

  for (int ci = 0; ci < nc; ++ci) {
    __syncthreads();                 // writes of buf[ci&1] visible; prior reads done
    const int cur = ci & 1;
    const bool more = (ci + 1) < nc;
    if (more) {                      // issue next chunk's global loads early
      const int k0 = (ci + 1) << 6;
      va = *(const uvec4*)(A + (size_t)(m0 + r) * lda + k0 + blk * 8);
#pragma unroll
      for (int s = 0; s < NS; ++s)
        vw[s] = *(const uvec4*)(Wp[s] + (size_t)(n0 + r) * ldw + k0 + blk * 8);
    }
    const unsigned short* Ab = As + cur * 2048;
    const unsigned short* Wb = Ws + cur * (NS * 2048);
#pragma unroll
    for (int kk = 0; kk < 2; ++kk) {
      bfrag af = *(const bfrag*)(Ab + (ra * 8 + ((kk * 4 + q) ^ (ra & 7))) * 8);
#pragma unroll
      for (int s = 0; s < NS; ++s) {
        bfrag wf = *(const bfrag*)(Wb + s * 2048 + (rw * 8 + ((kk * 4 + q) ^ (rw & 7))) * 8);
        acc[s] = mfma16(af, wf, acc[s]);
      }
    }
    if (more) {                      // stage next chunk into the other buffer
      const int nx = cur ^ 1;
      *(uvec4*)(As + nx * 2048 + wrOff) = va;
#pragma unroll
      for (int s = 0; s < NS; ++s)
        *(uvec4*)(Ws + nx * (NS * 2048) + s * 2048 + wrOff) = vw[s];
    }
  }
  __syncthreads();                   // protect LDS for a following stream
}

// ---- fp32 -> bf16 bulk convert (n divisible by 1024) ----
__global__ void k_cvt(const float* __restrict__ s, unsigned short* __restrict__ d, int n) {
  int i = blockIdx.x * blockDim.x + threadIdx.x;
  float4 v = ((const float4*)s)[i];
  unsigned int u0 = (unsigned int)f2b(v.x) | ((unsigned int)f2b(v.y) << 16);
  unsigned int u1 = (unsigned int)f2b(v.z) | ((unsigned int)f2b(v.w) << 16);
  ((uint2*)d)[i] = make_uint2(u0, u1);
}

// ---- LLM diagnosis mask: mask[b,c] = (c in llm_idx[b,:]) ----
__global__ void k_mask(const int* __restrict__ llm, float* __restrict__ outm) {
  int c = blockIdx.x * 256 + threadIdx.x;
  int b = blockIdx.y;
  if (c >= nC) return;
  const int* lr = llm + b * nND;
  float v = 0.f;
#pragma unroll
  for (int i = 0; i < nND; ++i) v = (lr[i] == c) ? 1.f : v;
  outm[(size_t)b * nC + c] = v;
}

// ---- sparse visit embedding: ve[b,t,:] = sum_{c: Hs[b,c,t]!=0} Hs*emb[c,:] ----
// One block per patient b; wave w owns t-quarter [16w,16w+16). Lane layout per
// c-group of 4: lane = (c_off<<4)|t_local -> fully coalesced 256B reads of Hs.
// Wave-private LDS tiles -> no atomics, deterministic accumulation order.
__global__ void k_embed(const float* __restrict__ Hs, const float* __restrict__ emb,
                        unsigned short* __restrict__ ve) {
  __shared__ float tile[4][16][128];
  const int b = blockIdx.x;
  const int tid = threadIdx.x;
  const int w = tid >> 6, lane = tid & 63;
  float* tw = &tile[w][0][0];
  for (int i = lane; i < 16 * 128; i += 64) tw[i] = 0.f;
  const float* hb = Hs + (size_t)b * nC * nT;
  const int tq = w * 16;
  const int tl = lane & 15;
  const int co = lane >> 4;
  for (int cb = 0; cb < nC; cb += 4) {
    const int c = cb + co;
    float v = hb[(size_t)c * nT + tq + tl];
    unsigned long long m = __ballot(v != 0.f);
    while (m) {
      const int p = __ffsll(m) - 1;
      m &= m - 1;
      const int cc = cb + (p >> 4);
      const int tt = p & 15;
      const float vv = __shfl(v, p);
      const float* er = emb + (size_t)cc * nD;
      tile[w][tt][lane]      += vv * er[lane];
      tile[w][tt][lane + 64] += vv * er[lane + 64];
    }
  }
  for (int rr = 0; rr < 16; ++rr) {
    unsigned short* o = ve + ((size_t)b * nT + tq + rr) * nD;
    o[lane]      = f2b(tile[w][rr][lane]);
    o[lane + 64] = f2b(tile[w][rr][lane + 64]);
  }
}

// ---- one GRU step (fused gi = ve@Wih^T + gh = h@Whh^T + gate update) ----
__global__ __launch_bounds__(256) void k_gru(
    int t,
    const unsigned short* __restrict__ hib, const float* __restrict__ hif,
    const unsigned short* __restrict__ ve,
    const unsigned short* __restrict__ Whh, const unsigned short* __restrict__ Wih,
    const float* __restrict__ bih, const float* __restrict__ bhh,
    float* __restrict__ hof, unsigned short* __restrict__ hob,
    unsigned short* __restrict__ hsb) {
  __shared__ __align__(16) unsigned short As[2 * 2048];
  __shared__ __align__(16) unsigned short Ws[2 * 3 * 2048];
  const int tid = threadIdx.x, lane = tid & 63, w = tid >> 6;
  const int mq = w & 1, nq = w >> 1;
  const int m0 = blockIdx.x * 32, n0 = blockIdx.y * 32;

  ffrag acc1[3] = {};  // h-side: r, z, h_n
  const unsigned short* const Wp1[3] = {Whh, Whh + (size_t)nH * nH, Whh + (size_t)2 * nH * nH};
  mm_stream<3>(acc1, hib, nH, nH, Wp1, nH, m0, n0, tid, lane, mq, nq, As, Ws);
  ffrag acc2[3] = {};  // ve-side: r, z, i_n
  const unsigned short* const Wp2[3] = {Wih, Wih + (size_t)nH * nD, Wih + (size_t)2 * nH * nD};
  mm_stream<3>(acc2, ve + (size_t)t * nD, nT * nD, nD, Wp2, nD, m0, n0, tid, lane, mq, nq, As, Ws);

  const int col = n0 + nq * 16 + (lane & 15);
  const int rb = m0 + mq * 16 + ((lane >> 4) << 2);
  const float b_r = bih[col] + bhh[col];
  const float b_z = bih[nH + col] + bhh[nH + col];
  const float bi_n = bih[2 * nH + col];
  const float bh_n = bhh[2 * nH + col];
#pragma unroll
  for (int i = 0; i < 4; ++i) {
    const int row = rb + i;
    const size_t idx = (size_t)row * nH + col;
    const float rr = sigm(acc1[0][i] + acc2[0][i] + b_r);
    const float zv = sigm(acc1[1][i] + acc2[1][i] + b_z);
    const float nn = tanhf(acc2[2][i] + bi_n + rr * (acc1[2][i] + bh_n));
    const float hold = hif[idx];
    const float hnew = (1.f - zv) * nn + zv * hold;
    hof[idx] = hnew;
    const unsigned short h16 = f2b(hnew);
    hob[idx] = h16;
    hsb[((size_t)row * nT + t) * nH + col] = h16;
  }
}

// ---- attention pooling: alpha = softmax(hs@attn_w), henc = sum_t alpha*hs ----
__global__ void k_attn(const unsigned short* __restrict__ hsb,
                       const float* __restrict__ aw,
                       unsigned short* __restrict__ hencb) {
  __shared__ float sc[nT];
  __shared__ float al[nT];
  const int b = blockIdx.x;
  const int tid = threadIdx.x;
  const int w = tid >> 6, lane = tid & 63;
  for (int t = w; t < nT; t += 4) {
    const unsigned short* hr = hsb + ((size_t)b * nT + t) * nH;
    float s = 0.f;
    for (int i = lane; i < nH; i += 64) s += b2f(hr[i]) * aw[i];
#pragma unroll
    for (int o = 32; o > 0; o >>= 1) s += __shfl_xor(s, o);
    if (lane == 0) sc[t] = s;
  }
  __syncthreads();
  if (tid < nT) {
    float v = sc[tid];
    float mx = v;
#pragma unroll
    for (int o = 32; o > 0; o >>= 1) mx = fmaxf(mx, __shfl_xor(mx, o));
    float e = expf(v - mx);
    float su = e;
#pragma unroll
    for (int o = 32; o > 0; o >>= 1) su += __shfl_xor(su, o);
    al[tid] = e / su;
  }
  __syncthreads();
  for (int col = tid; col < nH; col += 256) {
    float a = 0.f;
    for (int t = 0; t < nT; ++t) a += al[t] * b2f(hsb[((size_t)b * nT + t) * nH + col]);
    hencb[(size_t)b * nH + col] = f2b(a);
  }
}

// ---- VAE head: mu/logvar matmuls + reparameterize; z0 -> ODE state ----
__global__ __launch_bounds__(256) void k_vae(
    const unsigned short* __restrict__ hencb,
    const unsigned short* __restrict__ Wmu, const unsigned short* __restrict__ Wvar,
    const float* __restrict__ bmu, const float* __restrict__ bvar,
    const float* __restrict__ eps,
    float* __restrict__ hf, unsigned short* __restrict__ hb,
    const int* __restrict__ lidx, float* __restrict__ out) {
  __shared__ __align__(16) unsigned short As[2 * 2048];
  __shared__ __align__(16) unsigned short Ws[2 * 2 * 2048];
  const int tid = threadIdx.x, lane = tid & 63, w = tid >> 6;
  const int mq = w & 1, nq = w >> 1;
  const int m0 = blockIdx.x * 32, n0 = blockIdx.y * 32;
  ffrag acc[2] = {};
  const unsigned short* const Wp[2] = {Wmu, Wvar};
  mm_stream<2>(acc, hencb, nH, nH, Wp, nH, m0, n0, tid, lane, mq, nq, As, Ws);
  const int col = n0 + nq * 16 + (lane & 15);
  const int rb = m0 + mq * 16 + ((lane >> 4) << 2);
#pragma unroll
  for (int i = 0; i < 4; ++i) {
    const int row = rb + i;
    const size_t idx = (size_t)row * nH + col;
    const float mu = acc[0][i] + bmu[col];
    const float lv = acc[1][i] + bvar[col];
    const float z0 = mu + expf(0.5f * lv) * eps[idx];
    hf[idx] = z0;
    hb[idx] = f2b(z0);
    if (lidx[row] == 0) out[idx] = z0;  // pred_z[b, 0]
  }
}

// ---- ODE f-eval part 1: zz = sigmoid(h_st @ Whz^T); g = zz * h_st ----
__global__ __launch_bounds__(256) void k_ode1(
    const unsigned short* __restrict__ hstb, const float* __restrict__ hstf,
    const unsigned short* __restrict__ Whz,
    float* __restrict__ zz, unsigned short* __restrict__ gb) {
  __shared__ __align__(16) unsigned short As[2 * 2048];
  __shared__ __align__(16) unsigned short Ws[2 * 2048];
  const int tid = threadIdx.x, lane = tid & 63, w = tid >> 6;
  const int mq = w & 1, nq = w >> 1;
  const int m0 = blockIdx.x * 32, n0 = blockIdx.y * 32;
  ffrag acc[1] = {};
  const unsigned short* const Wp[1] = {Whz};
  mm_stream<1>(acc, hstb, nH, nH, Wp, nH, m0, n0, tid, lane, mq, nq, As, Ws);
  const int col = n0 + nq * 16 + (lane & 15);
  const int rb = m0 + mq * 16 + ((lane >> 4) << 2);
#pragma unroll
  for (int i = 0; i < 4; ++i) {
    const size_t idx = (size_t)(rb + i) * nH + col;
    const float zv = sigm(acc[0][i]);
    zz[idx] = zv;
    gb[idx] = f2b(zv * hstf[idx]);
  }
}

// ---- ODE f-eval part 2 + RK4 stage combine ----
// nn = tanh(g @ Whn^T); f = (1-zz)*(nn - h_st); then per-stage update.
// NOTE: hstf/htf/hbf may alias across stages; per-element read-before-write by
// the owning thread only, so no __restrict__ on them.
template<int STG>
__global__ __launch_bounds__(256) void k_ode2(
    const unsigned short* __restrict__ gbb, const unsigned short* __restrict__ Whn,
    const float* __restrict__ zz, const float* hstf,
    float* hbf, unsigned short* __restrict__ hbb,
    float* htf, unsigned short* __restrict__ htb,
    float* __restrict__ kacc,
    const float* __restrict__ ts, int s,
    const int* __restrict__ lidx, float* __restrict__ out) {
  __shared__ __align__(16) unsigned short As[2 * 2048];
  __shared__ __align__(16) unsigned short Ws[2 * 2048];
  const int tid = threadIdx.x, lane = tid & 63, w = tid >> 6;
  const int mq = w & 1, nq = w >> 1;
  const int m0 = blockIdx.x * 32, n0 = blockIdx.y * 32;
  ffrag acc[1] = {};
  const unsigned short* const Wp[1] = {Whn};
  mm_stream<1>(acc, gbb, nH, nH, Wp, nH, m0, n0, tid, lane, mq, nq, As, Ws);
  const float dt = ts[s + 1] - ts[s];
  const int col = n0 + nq * 16 + (lane & 15);
  const int rb = m0 + mq * 16 + ((lane >> 4) << 2);
#pragma unroll
  for (int i = 0; i < 4; ++i) {
    const int row = rb + i;
    const size_t idx = (size_t)row * nH + col;
    const float nn = tanhf(acc[0][i]);
    const float zv = zz[idx];
    const float fv = (1.f - zv) * (nn - hstf[idx]);
    if (STG == 0) {
      kacc[idx] = fv;
      const float ht = hbf[idx] + 0.5f * dt * fv;
      htf[idx] = ht; htb[idx] = f2b(ht);
    } else if (STG == 1) {
      kacc[idx] += 2.f * fv;
      const float ht = hbf[idx] + 0.5f * dt * fv;
      htf[idx] = ht; htb[idx] = f2b(ht);
    } else if (STG == 2) {
      kacc[idx] += 2.f * fv;
      const float ht = hbf[idx] + dt * fv;
      htf[idx] = ht; htb[idx] = f2b(ht);
    } else {
      const float hn = hbf[idx] + (dt * (1.f / 6.f)) * (kacc[idx] + fv);
      hbf[idx] = hn; hbb[idx] = f2b(hn);
      if (lidx[row] == s + 1) out[idx] = hn;  // pred_z[b, s+1]
    }
  }
}

}  // namespace

extern "C" void kernel_launch(void* const* d_in, const int* in_sizes, int n_in,
                              void* d_out, int out_size, void* d_ws, size_t ws_size,
                              hipStream_t stream) {
  const float* Hs   = (const float*)d_in[0];
  const float* ts   = (const float*)d_in[1];
  const int*   lidx = (const int*)d_in[2];
  const int*   llm  = (const int*)d_in[3];
  const float* eps  = (const float*)d_in[4];
  const float* emb  = (const float*)d_in[5];
  const float* Wih  = (const float*)d_in[6];
  const float* Whh  = (const float*)d_in[7];
  const float* bih  = (const float*)d_in[8];
  const float* bhh  = (const float*)d_in[9];
  const float* aw   = (const float*)d_in[10];
  const float* Wmu  = (const float*)d_in[11];
  const float* bmu  = (const float*)d_in[12];
  const float* Wvar = (const float*)d_in[13];
  const float* bvar = (const float*)d_in[14];
  const float* Whz  = (const float*)d_in[15];
  const float* Whn  = (const float*)d_in[16];

  float* out_last = (float*)d_out;
  float* out_mask = out_last + (size_t)nB * nH;

  char* p = (char*)d_ws;
  auto alloc = [&](size_t bytes) {
    void* r = p; p += (bytes + 255) & ~(size_t)255; return r;
  };
  unsigned short* Whh_b  = (unsigned short*)alloc((size_t)3 * nH * nH * 2);
  unsigned short* Wih_b  = (unsigned short*)alloc((size_t)3 * nH * nD * 2);
  unsigned short* Wmu_b  = (unsigned short*)alloc((size_t)nH * nH * 2);
  unsigned short* Wvar_b = (unsigned short*)alloc((size_t)nH * nH * 2);
  unsigned short* Whz_b  = (unsigned short*)alloc((size_t)nH * nH * 2);
  unsigned short* Whn_b  = (unsigned short*)alloc((size_t)nH * nH * 2);
  unsigned short* ve_b   = (unsigned short*)alloc((size_t)nB * nT * nD * 2);
  unsigned short* hs_b   = (unsigned short*)alloc((size_t)nB * nT * nH * 2);
  float* h0f             = (float*)alloc((size_t)nB * nH * 4);
  float* h1f             = (float*)alloc((size_t)nB * nH * 4);
  unsigned short* h0b    = (unsigned short*)alloc((size_t)nB * nH * 2);
  unsigned short* h1b    = (unsigned short*)alloc((size_t)nB * nH * 2);
  float* htf             = (float*)alloc((size_t)nB * nH * 4);
  unsigned short* htb    = (unsigned short*)alloc((size_t)nB * nH * 2);
  float* zzf             = (float*)alloc((size_t)nB * nH * 4);
  unsigned short* gb     = (unsigned short*)alloc((size_t)nB * nH * 2);
  float* kacc            = (float*)alloc((size_t)nB * nH * 4);
  unsigned short* hencb  = (unsigned short*)alloc((size_t)nB * nH * 2);

  hipMemsetAsync(h0f, 0, (size_t)nB * nH * 4, stream);   // GRU h0 = 0
  hipMemsetAsync(h0b, 0, (size_t)nB * nH * 2, stream);

  auto cvt = [&](const float* s, unsigned short* d, int n) {
    k_cvt<<<n / 1024, 256, 0, stream>>>(s, d, n);
  };
  cvt(Whh, Whh_b, 3 * nH * nH);
  cvt(Wih, Wih_b, 3 * nH * nD);
  cvt(Wmu, Wmu_b, nH * nH);
  cvt(Wvar, Wvar_b, nH * nH);
  cvt(Whz, Whz_b, nH * nH);
  cvt(Whn, Whn_b, nH * nH);

  k_embed<<<nB, 256, 0, stream>>>(Hs, emb, ve_b);
  k_mask<<<dim3((nC + 255) / 256, nB), 256, 0, stream>>>(llm, out_mask);

  const dim3 gg(nB / 32, nH / 32);  // 8 x 32 = 256 blocks
  for (int t = 0; t < nT; ++t) {
    const unsigned short* hib = (t & 1) ? h1b : h0b;
    const float* hif = (t & 1) ? h1f : h0f;
    unsigned short* hob = (t & 1) ? h0b : h1b;
    float* hof = (t & 1) ? h0f : h1f;
    k_gru<<<gg, 256, 0, stream>>>(t, hib, hif, ve_b, Whh_b, Wih_b, bih, bhh,
                                  hof, hob, hs_b);
  }
  k_attn<<<nB, 256, 0, stream>>>(hs_b, aw, hencb);
  k_vae<<<gg, 256, 0, stream>>>(hencb, Wmu_b, Wvar_b, bmu, bvar, eps,
                                h0f, h0b, lidx, out_last);

  for (int s = 0; s < nNT - 1; ++s) {
    k_ode1<<<gg, 256, 0, stream>>>(h0b, h0f, Whz_b, zzf, gb);
    k_ode2<0><<<gg, 256, 0, stream>>>(gb, Whn_b, zzf, h0f, h0f, h0b, htf, htb,
                                      kacc, ts, s, lidx, out_last);
    k_ode1<<<gg, 256, 0, stream>>>(htb, htf, Whz_b, zzf, gb);
    k_ode2<1><<<gg, 256, 0, stream>>>(gb, Whn_b, zzf, htf, h0f, h0b, htf, htb,
                                      kacc, ts, s, lidx, out_last);
    k_ode1<<<gg, 256, 0, stream>>>(htb, htf, Whz_b, zzf, gb);
    k_ode2<2><<<gg, 256, 0, stream>>>(gb, Whn_b, zzf, htf, h0f, h0b, htf, htb,
                                      kacc, ts, s, lidx, out_last);
    k_ode1<<<gg, 256, 0, stream>>>(htb, htf, Whz_b, zzf, gb);
    k_ode2<3><<<gg, 256, 0, stream>>>(gb, Whn_b, zzf, htf, h0f, h0b, htf, htb,
                                      kacc, ts, s, lidx, out_last);
  }
}